// Round 1
// baseline (217.307 us; speedup 1.0000x reference)
//
#include <hip/hip_runtime.h>
#include <hip/hip_bf16.h>

// Problem constants
#define B_   2
#define N_   2048
#define D_   128
#define H_   16
#define ALL_ 2048
#define M_   (B_*N_)    // 4096 total rows
#define BH_  (B_*H_)    // 32 (batch*heads)

typedef __bf16 bf16;
typedef __bf16 bf16x8 __attribute__((ext_vector_type(8)));
typedef __bf16 bf16x4 __attribute__((ext_vector_type(4)));
typedef float  floatx4 __attribute__((ext_vector_type(4)));

#define MFMA32K(a,b,c) __builtin_amdgcn_mfma_f32_16x16x32_bf16((a),(b),(c),0,0,0)

// async global->LDS DMA, 16B per lane (m97 pattern).
// Global address is PER-LANE (base + lane*8 bf16); LDS addr wave-uniform.
__device__ inline void load_lds16(const bf16* g, bf16* l) {
    __builtin_amdgcn_global_load_lds((const __attribute__((address_space(1))) void*)g,
                                     (__attribute__((address_space(3))) void*)l, 16, 0, 0);
}

#define WAITCNT_VM(n) ((0xF << 8) | (0x7 << 4) | (n))

// ---------------------------------------------------------------------------
// FRAGMENT-MAJOR LAYOUTS:
//  A/B-frag canonical (16x16x32): elem j of lane (lrow=lane&15,quad=lane>>4)
//    A[m=lrow][k=kf*32+quad*8+j]  /  B[k=kf*32+quad*8+j][n=lrow]
//  Wf  (Wq/Wk/Wv): [ct 128][kf 4][lane][8]  canonical
//  xf:  [rt 256][kf 4][lane][8]             canonical
//  Qf/Kf: [bh][t 128][kf 4][lane][8]        canonical
//  Vf:  [bh][kb 32][nf 8][g 2][lane][8]  PERMUTED k:
//        elem j = V[key=kb*64+(2g+(j>>2))*16+quad*4+(j&3)][d=nf*16+lrow]
//  ctxf: [qt 256][kf 64][lane][8]        PERMUTED k (same map over d):
//        elem j = ctx[q=qt*16+lrow][d' = (kf&3)*32+(j>>2)*16+quad*4+(j&3)]
//        (head = kf>>2) — written DIRECTLY from flash O accumulators
//        (concat of nf-pair floatx4s), no LDS reshape.
//  Wof: [ct 8][kf 64][lane][8]           PERMUTED k to MATCH ctxf:
//        elem j = Wo[k = kf*32+(j>>2)*16+quad*4+(j&3)][col=ct*16+lrow]
//  MFMA contraction is invariant when A and B agree on the k-permutation.
//  mbias pre-scaled by log2(e) (exp2 path).
// ---------------------------------------------------------------------------

// ---------------------------------------------------------------------------
// Kernel T: prep — unchanged from R17.
// ---------------------------------------------------------------------------
__global__ __launch_bounds__(256) void prep_weights(const float* __restrict__ x,
                                                    const float* __restrict__ Wq,
                                                    const float* __restrict__ Wk,
                                                    const float* __restrict__ Wv,
                                                    const float* __restrict__ Wo,
                                                    const int* __restrict__ mask,
                                                    bf16* __restrict__ Wqf,
                                                    bf16* __restrict__ Wkf,
                                                    bf16* __restrict__ Wvf,
                                                    bf16* __restrict__ Wof,
                                                    bf16* __restrict__ xf,
                                                    float* __restrict__ mbias) {
    __shared__ bf16 pw[16896];
    int bid = blockIdx.x, t = threadIdx.x;
    int lane = t & 63, wave = t >> 6;
    int lrow = lane & 15, quad = lane >> 4;

    if (bid < 192) {
        // ---- Wq/Wk/Wv [128][2048]: block = 64 k-rows (half) x 64 cols ----
        int m = bid / 64, rest = bid % 64;
        int cg = rest >> 1, kh = rest & 1;
        const float* W = (m == 0) ? Wq : (m == 1) ? Wk : Wv;
        bf16* Wf       = (m == 0) ? Wqf : (m == 1) ? Wkf : Wvf;
        int slot = t & 15, rowb = t >> 4;
#pragma unroll
        for (int i = 0; i < 4; i++) {
            int rl_ = rowb + i * 16;           // local k-row 0..63
            float4 v = *(const float4*)(W + (size_t)(kh * 64 + rl_) * 2048 + cg * 64 + slot * 4);
            bf16x4 o; o[0]=(bf16)v.x; o[1]=(bf16)v.y; o[2]=(bf16)v.z; o[3]=(bf16)v.w;
            *(bf16x4*)(&pw[rl_ * 68 + slot * 4]) = o;   // tile [k 64][col 64] stride 68
        }
        __syncthreads();
        int ctl = wave;                        // local col-tile 0..3
#pragma unroll
        for (int kfl = 0; kfl < 2; kfl++) {
            bf16x8 w;
#pragma unroll
            for (int j = 0; j < 8; j++) w[j] = pw[(kfl * 32 + quad * 8 + j) * 68 + ctl * 16 + lrow];
            *(bf16x8*)(Wf + (size_t)((cg * 4 + ctl) * 4 + kh * 2 + kfl) * 512 + lane * 8) = w;
        }
    } else if (bid < 224) {
        // ---- Wo [2048][128]: block = 128 k-rows x 64-col half, PERMUTED ----
        int idx = bid - 192;
        int kb16 = idx >> 1, ch = idx & 1;
        int k0 = kb16 * 128;
        int slot = t & 15, rowb = t >> 4;
#pragma unroll
        for (int i = 0; i < 8; i++) {
            int r = rowb + i * 16;             // 0..127
            float4 v = *(const float4*)(Wo + (size_t)(k0 + r) * 128 + ch * 64 + slot * 4);
            bf16x4 o; o[0]=(bf16)v.x; o[1]=(bf16)v.y; o[2]=(bf16)v.z; o[3]=(bf16)v.w;
            *(bf16x4*)(&pw[r * 68 + slot * 4]) = o;     // tile [k 128][col 64] stride 68
        }
        __syncthreads();
        int ctl = wave;
        int ct = ch * 4 + ctl;
#pragma unroll
        for (int kfl = 0; kfl < 4; kfl++) {
            bf16x8 w;
            // PERMUTED k to match flash's O-concat A-frags:
            // elem j <- k = kfl*32 + (j>>2)*16 + quad*4 + (j&3)
#pragma unroll
            for (int j = 0; j < 8; j++)
                w[j] = pw[(kfl * 32 + ((j >> 2) << 4) + quad * 4 + (j & 3)) * 68 + ctl * 16 + lrow];
            *(bf16x8*)(Wof + (size_t)(ct * 64 + kb16 * 4 + kfl) * 512 + lane * 8) = w;
        }
    } else if (bid < 352) {
        // ---- x [4096][128] fp32 -> xf frags, 32 rows per block ----
        int idx = bid - 224, r0 = idx * 32;
        int slot = t & 31, rowb = t >> 5;
#pragma unroll
        for (int i = 0; i < 4; i++) {
            int r = rowb + i * 8;              // 0..31
            float4 v = *(const float4*)(x + (size_t)(r0 + r) * 128 + slot * 4);
            bf16x4 o; o[0]=(bf16)v.x; o[1]=(bf16)v.y; o[2]=(bf16)v.z; o[3]=(bf16)v.w;
            *(bf16x4*)(&pw[r * 136 + slot * 4]) = o;    // tile [row 32][col 128] stride 136
        }
        __syncthreads();
        int rtl = wave >> 1;                   // 2 row-tiles of 16
        int kf2 = (wave & 1) * 2;
#pragma unroll
        for (int kfl = 0; kfl < 2; kfl++) {
            int kf = kf2 + kfl;
            bf16x8 w = *(const bf16x8*)(&pw[(rtl * 16 + lrow) * 136 + kf * 32 + quad * 8]);
            *(bf16x8*)(xf + (size_t)((idx * 2 + rtl) * 4 + kf) * 512 + lane * 8) = w;
        }
    } else {
        int e = (bid - 352) * 256 + t;
        // log2-domain: exp2(-43.28) ~ 9e-14 ~ 0
        mbias[e] = mask[e] ? 0.0f : -43.2808512f;
    }
}

// ---------------------------------------------------------------------------
// Kernel A: Q/K/V projection — unchanged from R16.
// ---------------------------------------------------------------------------
__global__ __launch_bounds__(256) void qkv_proj(const bf16* __restrict__ xf,
                                                const float* __restrict__ bq,
                                                const float* __restrict__ bk,
                                                const float* __restrict__ bv,
                                                const bf16* __restrict__ Wqf,
                                                const bf16* __restrict__ Wkf,
                                                const bf16* __restrict__ Wvf,
                                                bf16* __restrict__ Qf,
                                                bf16* __restrict__ Kf,
                                                bf16* __restrict__ Vf) {
    __shared__ bf16 tile[64][72];

    int z = blockIdx.z;
    const float* bias = (z == 0) ? bq : (z == 1) ? bk : bv;
    const bf16*  Wf   = (z == 0) ? Wqf : (z == 1) ? Wkf : Wvf;

    int tid = threadIdx.x;
    int wave = tid >> 6, lane = tid & 63;
    int lrow = lane & 15, quad = lane >> 4;
    int r0b = blockIdx.x * 64;
    int c0 = blockIdx.y * 64;
    int cg4 = c0 >> 4;

    int rt = (r0b >> 4) + wave;
    bf16x8 a[4];
#pragma unroll
    for (int kf = 0; kf < 4; kf++)
        a[kf] = *(const bf16x8*)(xf + (size_t)(rt * 4 + kf) * 512 + lane * 8);

    int bb = r0b >> 11;
    int h  = c0 >> 7;
    int bhw = bb * 16 + h;
    int tile16 = (r0b & 2047) >> 4;
    int kbt = (r0b & 2047) >> 6;
    floatx4 zero4 = {0.f, 0.f, 0.f, 0.f};

    floatx4 acc[4] = {zero4, zero4, zero4, zero4};
#pragma unroll
    for (int kf = 0; kf < 4; kf++) {
#pragma unroll
        for (int nf = 0; nf < 4; nf++) {
            bf16x8 b = *(const bf16x8*)(Wf + (size_t)((cg4 + nf) * 4 + kf) * 512 + lane * 8);
            acc[nf] = MFMA32K(a[kf], b, acc[nf]);
        }
    }

#pragma unroll
    for (int nf = 0; nf < 4; nf++) {
        int col = nf * 16 + lrow;
        float bvv = bias[c0 + col];
#pragma unroll
        for (int r = 0; r < 4; r++) {
            int row = wave * 16 + quad * 4 + r;
            bf16 val = (bf16)(acc[nf][r] + bvv);
            if (z < 2) tile[row][col] = val;
            else       tile[col][row] = val;
        }
    }
    __syncthreads();

    if (z < 2) {
        bf16* dst = (z == 0) ? Qf : Kf;
        int s = wave;
        int kfbase = (c0 & 127) >> 5;
        size_t fbase = ((size_t)bhw * 128 + tile16 + s) * 4 + kfbase;
#pragma unroll
        for (int kfl = 0; kfl < 2; kfl++) {
            bf16x8 w = *(const bf16x8*)(&tile[s * 16 + lrow][kfl * 32 + quad * 8]);
            *(bf16x8*)(dst + (fbase + kfl) * 512 + lane * 8) = w;
        }
    } else {
        int nfl = wave;
        int nfbase = (c0 & 127) >> 4;
        size_t fbase = (((size_t)bhw * 32 + kbt) * 8 + (nfbase + nfl)) * 2;
#pragma unroll
        for (int g = 0; g < 2; g++) {
            bf16x4 a0 = *(const bf16x4*)(&tile[nfl * 16 + lrow][g * 32 + quad * 4]);
            bf16x4 a1 = *(const bf16x4*)(&tile[nfl * 16 + lrow][g * 32 + 16 + quad * 4]);
            bf16x8 w;
            w[0]=a0[0]; w[1]=a0[1]; w[2]=a0[2]; w[3]=a0[3];
            w[4]=a1[0]; w[5]=a1[1]; w[6]=a1[2]; w[7]=a1[3];
            *(bf16x8*)(Vf + (fbase + g) * 512 + lane * 8) = w;
        }
    }
}

// ---------------------------------------------------------------------------
// Kernel B: flash attention — KVBLK 64 -> 32 for occupancy.
// LDS was 73728 B (2 blocks/CU = 2 waves/SIMD); rocprof showed the iteration
// wall time ~= LDS-read cycles + MFMA cycles SERIALIZED (MfmaUtil 34.5%,
// VALUBusy 32%, Occupancy 19.5%) — the ds_read->MFMA chain can't be hidden
// by 2 waves/SIMD. A 32-key tile is one g-slice of the existing Vf
// permutation: per-key LDS traffic, MFMA count, DMA bytes and the FP
// summation order are all EXACTLY conserved; only LDS shrinks to
// 40960 B -> 4 blocks/CU = 4 waves/SIMD. setprio(1) wraps the MFMA
// clusters (T5: inter-block wave diversity now exists).
// ---------------------------------------------------------------------------
__global__ __launch_bounds__(256) void flash_attn(const bf16* __restrict__ Qf,
                                                  const bf16* __restrict__ Kf,
                                                  const bf16* __restrict__ Vf,
                                                  const float* __restrict__ mbias,
                                                  const int* __restrict__ mask,
                                                  bf16* __restrict__ ctxf) {
    // [0,8192): buf0 K|V   [8192,16384): buf1 K|V   (elems; 4096 K + 4096 V)
    __shared__ bf16 sm[16384];
    __shared__ float mbL[2048];    // mbias row for this batch (8KB)

    int tid = threadIdx.x;
    int wave = tid >> 6, lane = tid & 63;
    int lrow = lane & 15, quad = lane >> 4;
    // XCD swizzle: 512 blocks = 8 xcd * (4 bh * 16 qblk)
    int bid = blockIdx.x;
    int xcd = bid & 7, seq = bid >> 3;          // seq 0..63
    int bh  = xcd * 4 + (seq >> 4);             // 0..31
    int qblk = seq & 15;                        // 0..15
    int b  = bh >> 4;
    int q0 = qblk * 128 + wave * 32;

    const float* mbp = mbias + b * N_;
    const bf16* kbase = Kf + (size_t)bh * 262144;
    const bf16* vbase = Vf + (size_t)bh * 262144;

    // Q B-frags from Qf (coalesced 16B loads), held all loop
    bf16x8 qf[2][4];
#pragma unroll
    for (int u = 0; u < 2; u++)
#pragma unroll
        for (int kf = 0; kf < 4; kf++)
            qf[u][kf] = *(const bf16x8*)(Qf + (size_t)(((size_t)bh * 128 + (q0 >> 4) + u) * 4 + kf) * 512 + lane * 8);

    bf16x8 ones;
#pragma unroll
    for (int j = 0; j < 8; j++) ones[j] = (bf16)1.0f;

    floatx4 zero4 = {0.f, 0.f, 0.f, 0.f};
    floatx4 O[2][8];
#pragma unroll
    for (int u = 0; u < 2; u++)
#pragma unroll
        for (int nf = 0; nf < 8; nf++) O[u][nf] = zero4;
    floatx4 Oext[2] = {zero4, zero4};   // row sums l[q] via ones-MFMA

    const float scale = 0.12751742f;    // (1/sqrt(128)) * log2(e)

    // ---- prologue: DMA tile 0 into buffer 0 + mbias row into LDS ----
    // K tile t: 8 contiguous frags at kbase + t*4096.
    // V tile t: kb64=t>>1, g=t&1: frag nf at vbase + kb64*8192 + nf*1024 + g*512.
#pragma unroll
    for (int i = 0; i < 2; i++) {
        int s = wave * 2 + i;                  // 0..7
        load_lds16(kbase + s * 512 + lane * 8, &sm[s * 512]);
        load_lds16(vbase + s * 1024 + lane * 8, &sm[4096 + s * 512]);
    }
#pragma unroll
    for (int i = 0; i < 2; i++) {
        int seg = wave * 2 + i;                // 0..7, 256 floats (1KB) each
        load_lds16((const bf16*)(mbp + seg * 256) + lane * 8, (bf16*)(mbL + seg * 256));
    }

    for (int t = 0; t < 64; t++) {
        int cur = (t & 1) << 13;               // elems: 0 or 8192

        // ---- 1./2. wait my DMA(t) (+prologue mbias on t==0), barrier ----
        __builtin_amdgcn_s_waitcnt(WAITCNT_VM(0));
        __builtin_amdgcn_s_barrier();

        // ---- 3. prefetch DMA(t+1) into the other buffer ----
        if (t < 63) {
            int nxt = cur ^ 8192;
            int tn = t + 1;
            const bf16* ksrc = kbase + (size_t)tn * 4096;
            const bf16* vsrc = vbase + (size_t)(tn >> 1) * 8192 + (size_t)(tn & 1) * 512;
#pragma unroll
            for (int i = 0; i < 2; i++) {
                int s = wave * 2 + i;
                load_lds16(ksrc + s * 512 + lane * 8, &sm[nxt + s * 512]);
                load_lds16(vsrc + s * 1024 + lane * 8, &sm[nxt + 4096 + s * 512]);
            }
        }

        // ---- 4. S^T per 16-key tile; exp2; pack into K=32 B-frags ----
        bf16x8 pf[2];
#pragma unroll
        for (int s = 0; s < 2; s++) {
            floatx4 S0 = zero4, S1 = zero4;
            __builtin_amdgcn_s_setprio(1);
#pragma unroll
            for (int kf = 0; kf < 4; kf++) {
                bf16x8 kfr = *(const bf16x8*)(&sm[cur + ((s * 4 + kf) * 64 + lane) * 8]);
                S0 = MFMA32K(kfr, qf[0][kf], S0);
                S1 = MFMA32K(kfr, qf[1][kf], S1);
            }
            __builtin_amdgcn_s_setprio(0);
            float4 mb4 = *(const float4*)(mbL + t * 32 + s * 16 + quad * 4);
            const float* mbr = (const float*)&mb4;
            int o = s * 4;
#pragma unroll
            for (int r = 0; r < 4; r++) {
                float p0 = __builtin_amdgcn_exp2f(fmaf(S0[r], scale, mbr[r]));
                float p1 = __builtin_amdgcn_exp2f(fmaf(S1[r], scale, mbr[r]));
                pf[0][o + r] = (bf16)p0;
                pf[1][o + r] = (bf16)p1;
            }
        }

        // ---- l row-sums via ones-MFMA ----
        Oext[0] = MFMA32K(ones, pf[0], Oext[0]);
        Oext[1] = MFMA32K(ones, pf[1], Oext[1]);

        // ---- PV: O^T[d][q] += V^T P, full-rate K=32 ----
        __builtin_amdgcn_s_setprio(1);
#pragma unroll
        for (int nf = 0; nf < 8; nf++) {
            bf16x8 vfr = *(const bf16x8*)(&sm[cur + 4096 + (nf * 64 + lane) * 8]);
            O[0][nf] = MFMA32K(vfr, pf[0], O[0][nf]);
            O[1][nf] = MFMA32K(vfr, pf[1], O[1][nf]);
        }
        __builtin_amdgcn_s_setprio(0);
        // no end-of-iter barrier: next iter's barrier (after vmcnt) protects
        // buf[nxt] — every wave reaching it has finished this iter's reads
    }

    // ---- epilogue: normalize + DIRECT permuted-concat A-frag stores ----
    const int* mp = mask + b * N_;
    int h4 = (bh & 15) * 4;
    size_t qtb = (size_t)b * 128 + (q0 >> 4);
#pragma unroll
    for (int u = 0; u < 2; u++) {
        float lsum = Oext[u][0];
        int q = q0 + u * 16 + lrow;
        float rl = (mp[q] && lsum > 0.f) ? (1.0f / lsum) : 0.f;
#pragma unroll
        for (int g = 0; g < 4; g++) {
            bf16x8 w;
#pragma unroll
            for (int j = 0; j < 4; j++) {
                w[j]     = (bf16)(O[u][2 * g][j]     * rl);
                w[j + 4] = (bf16)(O[u][2 * g + 1][j] * rl);
            }
            *(bf16x8*)(ctxf + ((qtb + u) * 64 + h4 + g) * 512 + lane * 8) = w;
        }
    }
}

// ---------------------------------------------------------------------------
// Kernel C: out = ctx @ Wo + bo, fp32 out. RESTRUCTURED: 256 blocks (one per
// 16-row qt), 4 waves split-K x4, each block computes ALL 128 cols from ONE
// ctxf row-tile read (was grid (256,4): 4 col-blocks each re-fetched the full
// 64KB qt tile -> 67MB for a 16.8MB tensor). Wof traffic unchanged
// (L2-resident). ctxf/Wof carry a matching k-permutation, opaque here.
// ---------------------------------------------------------------------------
__global__ __launch_bounds__(256) void out_proj(const bf16* __restrict__ ctxf,
                                                const bf16* __restrict__ Wof,
                                                const float* __restrict__ bo,
                                                float* __restrict__ out) {
    __shared__ float red[3 * 2048];    // waves 1..3 partials: [w][ct8][r4][lane64]
    int tid = threadIdx.x;
    int wave = tid >> 6, lane = tid & 63;
    int lrow = lane & 15, quad = lane >> 4;
    int qt = blockIdx.x;               // 16-row tile

    floatx4 zero4 = {0.f, 0.f, 0.f, 0.f};
    floatx4 acc[8] = {zero4, zero4, zero4, zero4, zero4, zero4, zero4, zero4};
    // wave w handles kf = w*16 .. w*16+15 (K 512 of 2048), all 8 col-tiles
    const bf16* ap = ctxf + ((size_t)qt * 64 + wave * 16) * 512 + lane * 8;
    const bf16* bp = Wof + ((size_t)wave * 16) * 512 + lane * 8;
#pragma unroll 4
    for (int kf = 0; kf < 16; kf++) {
        bf16x8 a = *(const bf16x8*)(ap + (size_t)kf * 512);
#pragma unroll
        for (int ct = 0; ct < 8; ct++) {
            bf16x8 w = *(const bf16x8*)(bp + ((size_t)ct * 64 + kf) * 512);
            acc[ct] = MFMA32K(a, w, acc[ct]);
        }
    }
    if (wave != 0) {
#pragma unroll
        for (int ct = 0; ct < 8; ct++)
#pragma unroll
            for (int r = 0; r < 4; r++)
                red[(wave - 1) * 2048 + ct * 256 + r * 64 + lane] = acc[ct][r];
    }
    __syncthreads();
    if (wave == 0) {
#pragma unroll
        for (int ct = 0; ct < 8; ct++) {
            int col = ct * 16 + lrow;
            float bv = bo[col];
#pragma unroll
            for (int r = 0; r < 4; r++) {
                int m = qt * 16 + quad * 4 + r;
                float s = acc[ct][r]
                        + red[0 * 2048 + ct * 256 + r * 64 + lane]
                        + red[1 * 2048 + ct * 256 + r * 64 + lane]
                        + red[2 * 2048 + ct * 256 + r * 64 + lane]
                        + bv;
                out[(size_t)m * 128 + col] = s;
            }
        }
    }
}

// ---------------------------------------------------------------------------
extern "C" void kernel_launch(void* const* d_in, const int* in_sizes, int n_in,
                              void* d_out, int out_size, void* d_ws, size_t ws_size,
                              hipStream_t stream) {
    const float* x    = (const float*)d_in[0];
    const int*   mask = (const int*)d_in[1];
    const float* Wq   = (const float*)d_in[2];
    const float* bq   = (const float*)d_in[3];
    const float* Wk   = (const float*)d_in[4];
    const float* bk   = (const float*)d_in[5];
    const float* Wv   = (const float*)d_in[6];
    const float* bv   = (const float*)d_in[7];
    const float* Wo   = (const float*)d_in[8];
    const float* bo   = (const float*)d_in[9];
    float* out = (float*)d_out;

    char* ws = (char*)d_ws;
    size_t off = 0;
    bf16* Wqf = (bf16*)(ws + off); off += (size_t)262144 * 2;
    bf16* Wkf = (bf16*)(ws + off); off += (size_t)262144 * 2;
    bf16* Wvf = (bf16*)(ws + off); off += (size_t)262144 * 2;
    bf16* Wof = (bf16*)(ws + off); off += (size_t)262144 * 2;
    bf16* xf  = (bf16*)(ws + off); off += (size_t)524288 * 2;
    size_t qkv_elems = (size_t)BH_ * N_ * 128;           // 8.4M
    bf16* Qf  = (bf16*)(ws + off); off += qkv_elems * 2; // fragment-major
    bf16* Kf  = (bf16*)(ws + off); off += qkv_elems * 2;
    bf16* Vf  = (bf16*)(ws + off); off += qkv_elems * 2;
    bf16* ctxf = (bf16*)(ws + off); off += (size_t)M_ * ALL_ * 2;
    float* mbias = (float*)(ws + off); off += (size_t)B_ * N_ * 4;
    (void)ws_size; (void)in_sizes; (void)n_in; (void)out_size;

    prep_weights<<<368, 256, 0, stream>>>(x, Wq, Wk, Wv, Wo, mask,
                                          Wqf, Wkf, Wvf, Wof, xf, mbias);

    qkv_proj<<<dim3(64, 32, 3), 256, 0, stream>>>(xf, bq, bk, bv, Wqf, Wkf, Wvf,
                                                  Qf, Kf, Vf);

    flash_attn<<<512, 256, 0, stream>>>(Qf, Kf, Vf, mbias, mask, ctxf);

    out_proj<<<256, 256, 0, stream>>>(ctxf, Wof, bo, out);
}

// Round 2
// 197.172 us; speedup vs baseline: 1.1021x; 1.1021x over previous
//
#include <hip/hip_runtime.h>
#include <hip/hip_bf16.h>

// Problem constants
#define B_   2
#define N_   2048
#define D_   128
#define H_   16
#define ALL_ 2048
#define M_   (B_*N_)    // 4096 total rows
#define BH_  (B_*H_)    // 32 (batch*heads)

typedef __bf16 bf16;
typedef __bf16 bf16x8 __attribute__((ext_vector_type(8)));
typedef __bf16 bf16x4 __attribute__((ext_vector_type(4)));
typedef float  floatx4 __attribute__((ext_vector_type(4)));

#define MFMA32K(a,b,c) __builtin_amdgcn_mfma_f32_16x16x32_bf16((a),(b),(c),0,0,0)

// async global->LDS DMA, 16B per lane (m97 pattern).
// Global address is PER-LANE (base + lane*8 bf16); LDS addr wave-uniform.
__device__ inline void load_lds16(const bf16* g, bf16* l) {
    __builtin_amdgcn_global_load_lds((const __attribute__((address_space(1))) void*)g,
                                     (__attribute__((address_space(3))) void*)l, 16, 0, 0);
}

#define WAITCNT_VM(n) ((0xF << 8) | (0x7 << 4) | (n))

// ---------------------------------------------------------------------------
// FRAGMENT-MAJOR LAYOUTS:
//  A/B-frag canonical (16x16x32): elem j of lane (lrow=lane&15,quad=lane>>4)
//    A[m=lrow][k=kf*32+quad*8+j]  /  B[k=kf*32+quad*8+j][n=lrow]
//  Wf  (Wq/Wk/Wv): [ct 128][kf 4][lane][8]  canonical
//  xf:  [rt 256][kf 4][lane][8]             canonical
//  Qf/Kf: [bh][t 128][kf 4][lane][8]        canonical
//  Vf:  [bh][kb 32][nf 8][g 2][lane][8]  PERMUTED k:
//        elem j = V[key=kb*64+(2g+(j>>2))*16+quad*4+(j&3)][d=nf*16+lrow]
//  ctxP: TWO partials (kh=0,1), each [qt 256][kf 64][lane][8] PERMUTED k
//        (same map over d) — written DIRECTLY from flash O accumulators.
//        Each partial is normalized by its OWN l; ls[kh][b][n][h] holds the
//        fp32 row-sums; out_proj blends A-frags: (l1*c1 + l2*c2)/(l1+l2).
//  Wof: [ct 8][kf 64][lane][8]           PERMUTED k to MATCH ctxP:
//        elem j = Wo[k = kf*32+(j>>2)*16+quad*4+(j&3)][col=ct*16+lrow]
//  MFMA contraction is invariant when A and B agree on the k-permutation.
//  mbias pre-scaled by log2(e) (exp2 path).
// ---------------------------------------------------------------------------

// ---------------------------------------------------------------------------
// Kernel T: prep — unchanged.
// ---------------------------------------------------------------------------
__global__ __launch_bounds__(256) void prep_weights(const float* __restrict__ x,
                                                    const float* __restrict__ Wq,
                                                    const float* __restrict__ Wk,
                                                    const float* __restrict__ Wv,
                                                    const float* __restrict__ Wo,
                                                    const int* __restrict__ mask,
                                                    bf16* __restrict__ Wqf,
                                                    bf16* __restrict__ Wkf,
                                                    bf16* __restrict__ Wvf,
                                                    bf16* __restrict__ Wof,
                                                    bf16* __restrict__ xf,
                                                    float* __restrict__ mbias) {
    __shared__ bf16 pw[16896];
    int bid = blockIdx.x, t = threadIdx.x;
    int lane = t & 63, wave = t >> 6;
    int lrow = lane & 15, quad = lane >> 4;

    if (bid < 192) {
        // ---- Wq/Wk/Wv [128][2048]: block = 64 k-rows (half) x 64 cols ----
        int m = bid / 64, rest = bid % 64;
        int cg = rest >> 1, kh = rest & 1;
        const float* W = (m == 0) ? Wq : (m == 1) ? Wk : Wv;
        bf16* Wf       = (m == 0) ? Wqf : (m == 1) ? Wkf : Wvf;
        int slot = t & 15, rowb = t >> 4;
#pragma unroll
        for (int i = 0; i < 4; i++) {
            int rl_ = rowb + i * 16;           // local k-row 0..63
            float4 v = *(const float4*)(W + (size_t)(kh * 64 + rl_) * 2048 + cg * 64 + slot * 4);
            bf16x4 o; o[0]=(bf16)v.x; o[1]=(bf16)v.y; o[2]=(bf16)v.z; o[3]=(bf16)v.w;
            *(bf16x4*)(&pw[rl_ * 68 + slot * 4]) = o;   // tile [k 64][col 64] stride 68
        }
        __syncthreads();
        int ctl = wave;                        // local col-tile 0..3
#pragma unroll
        for (int kfl = 0; kfl < 2; kfl++) {
            bf16x8 w;
#pragma unroll
            for (int j = 0; j < 8; j++) w[j] = pw[(kfl * 32 + quad * 8 + j) * 68 + ctl * 16 + lrow];
            *(bf16x8*)(Wf + (size_t)((cg * 4 + ctl) * 4 + kh * 2 + kfl) * 512 + lane * 8) = w;
        }
    } else if (bid < 224) {
        // ---- Wo [2048][128]: block = 128 k-rows x 64-col half, PERMUTED ----
        int idx = bid - 192;
        int kb16 = idx >> 1, ch = idx & 1;
        int k0 = kb16 * 128;
        int slot = t & 15, rowb = t >> 4;
#pragma unroll
        for (int i = 0; i < 8; i++) {
            int r = rowb + i * 16;             // 0..127
            float4 v = *(const float4*)(Wo + (size_t)(k0 + r) * 128 + ch * 64 + slot * 4);
            bf16x4 o; o[0]=(bf16)v.x; o[1]=(bf16)v.y; o[2]=(bf16)v.z; o[3]=(bf16)v.w;
            *(bf16x4*)(&pw[r * 68 + slot * 4]) = o;     // tile [k 128][col 64] stride 68
        }
        __syncthreads();
        int ctl = wave;
        int ct = ch * 4 + ctl;
#pragma unroll
        for (int kfl = 0; kfl < 4; kfl++) {
            bf16x8 w;
            // PERMUTED k to match flash's O-concat A-frags:
            // elem j <- k = kfl*32 + (j>>2)*16 + quad*4 + (j&3)
#pragma unroll
            for (int j = 0; j < 8; j++)
                w[j] = pw[(kfl * 32 + ((j >> 2) << 4) + quad * 4 + (j & 3)) * 68 + ctl * 16 + lrow];
            *(bf16x8*)(Wof + (size_t)(ct * 64 + kb16 * 4 + kfl) * 512 + lane * 8) = w;
        }
    } else if (bid < 352) {
        // ---- x [4096][128] fp32 -> xf frags, 32 rows per block ----
        int idx = bid - 224, r0 = idx * 32;
        int slot = t & 31, rowb = t >> 5;
#pragma unroll
        for (int i = 0; i < 4; i++) {
            int r = rowb + i * 8;              // 0..31
            float4 v = *(const float4*)(x + (size_t)(r0 + r) * 128 + slot * 4);
            bf16x4 o; o[0]=(bf16)v.x; o[1]=(bf16)v.y; o[2]=(bf16)v.z; o[3]=(bf16)v.w;
            *(bf16x4*)(&pw[r * 136 + slot * 4]) = o;    // tile [row 32][col 128] stride 136
        }
        __syncthreads();
        int rtl = wave >> 1;                   // 2 row-tiles of 16
        int kf2 = (wave & 1) * 2;
#pragma unroll
        for (int kfl = 0; kfl < 2; kfl++) {
            int kf = kf2 + kfl;
            bf16x8 w = *(const bf16x8*)(&pw[(rtl * 16 + lrow) * 136 + kf * 32 + quad * 8]);
            *(bf16x8*)(xf + (size_t)((idx * 2 + rtl) * 4 + kf) * 512 + lane * 8) = w;
        }
    } else {
        int e = (bid - 352) * 256 + t;
        // log2-domain: exp2(-43.28) ~ 9e-14 ~ 0
        mbias[e] = mask[e] ? 0.0f : -43.2808512f;
    }
}

// ---------------------------------------------------------------------------
// Kernel A: Q/K/V projection — unchanged.
// ---------------------------------------------------------------------------
__global__ __launch_bounds__(256) void qkv_proj(const bf16* __restrict__ xf,
                                                const float* __restrict__ bq,
                                                const float* __restrict__ bk,
                                                const float* __restrict__ bv,
                                                const bf16* __restrict__ Wqf,
                                                const bf16* __restrict__ Wkf,
                                                const bf16* __restrict__ Wvf,
                                                bf16* __restrict__ Qf,
                                                bf16* __restrict__ Kf,
                                                bf16* __restrict__ Vf) {
    __shared__ bf16 tile[64][72];

    int z = blockIdx.z;
    const float* bias = (z == 0) ? bq : (z == 1) ? bk : bv;
    const bf16*  Wf   = (z == 0) ? Wqf : (z == 1) ? Wkf : Wvf;

    int tid = threadIdx.x;
    int wave = tid >> 6, lane = tid & 63;
    int lrow = lane & 15, quad = lane >> 4;
    int r0b = blockIdx.x * 64;
    int c0 = blockIdx.y * 64;
    int cg4 = c0 >> 4;

    int rt = (r0b >> 4) + wave;
    bf16x8 a[4];
#pragma unroll
    for (int kf = 0; kf < 4; kf++)
        a[kf] = *(const bf16x8*)(xf + (size_t)(rt * 4 + kf) * 512 + lane * 8);

    int bb = r0b >> 11;
    int h  = c0 >> 7;
    int bhw = bb * 16 + h;
    int tile16 = (r0b & 2047) >> 4;
    int kbt = (r0b & 2047) >> 6;
    floatx4 zero4 = {0.f, 0.f, 0.f, 0.f};

    floatx4 acc[4] = {zero4, zero4, zero4, zero4};
#pragma unroll
    for (int kf = 0; kf < 4; kf++) {
#pragma unroll
        for (int nf = 0; nf < 4; nf++) {
            bf16x8 b = *(const bf16x8*)(Wf + (size_t)((cg4 + nf) * 4 + kf) * 512 + lane * 8);
            acc[nf] = MFMA32K(a[kf], b, acc[nf]);
        }
    }

#pragma unroll
    for (int nf = 0; nf < 4; nf++) {
        int col = nf * 16 + lrow;
        float bvv = bias[c0 + col];
#pragma unroll
        for (int r = 0; r < 4; r++) {
            int row = wave * 16 + quad * 4 + r;
            bf16 val = (bf16)(acc[nf][r] + bvv);
            if (z < 2) tile[row][col] = val;
            else       tile[col][row] = val;
        }
    }
    __syncthreads();

    if (z < 2) {
        bf16* dst = (z == 0) ? Qf : Kf;
        int s = wave;
        int kfbase = (c0 & 127) >> 5;
        size_t fbase = ((size_t)bhw * 128 + tile16 + s) * 4 + kfbase;
#pragma unroll
        for (int kfl = 0; kfl < 2; kfl++) {
            bf16x8 w = *(const bf16x8*)(&tile[s * 16 + lrow][kfl * 32 + quad * 8]);
            *(bf16x8*)(dst + (fbase + kfl) * 512 + lane * 8) = w;
        }
    } else {
        int nfl = wave;
        int nfbase = (c0 & 127) >> 4;
        size_t fbase = (((size_t)bhw * 32 + kbt) * 8 + (nfbase + nfl)) * 2;
#pragma unroll
        for (int g = 0; g < 2; g++) {
            bf16x4 a0 = *(const bf16x4*)(&tile[nfl * 16 + lrow][g * 32 + quad * 4]);
            bf16x4 a1 = *(const bf16x4*)(&tile[nfl * 16 + lrow][g * 32 + 16 + quad * 4]);
            bf16x8 w;
            w[0]=a0[0]; w[1]=a0[1]; w[2]=a0[2]; w[3]=a0[3];
            w[4]=a1[0]; w[5]=a1[1]; w[6]=a1[2]; w[7]=a1[3];
            *(bf16x8*)(Vf + (fbase + g) * 512 + lane * 8) = w;
        }
    }
}

// ---------------------------------------------------------------------------
// Kernel B: flash attention — SPLIT-K x2 over keys. R1 lesson: grid (512)
// was the occupancy binder, not LDS. This softmax has NO running max (pure
// sum of exp2), so key-splitting is exactly associative: each half writes
// ctx_i = O_i/l_i (bf16) + l_i (fp32); out_proj blends
// (l1*c1 + l2*c2)/(l1+l2). Grid 1024 (32bh x 16qblk x 2kh), KVBLK=32,
// LDS 36864 B -> 4 blocks/CU by LDS AND grid (>=3 by regs). Per-key LDS
// traffic / MFMA count / summation order conserved within a half.
// ---------------------------------------------------------------------------
__global__ __launch_bounds__(256) void flash_attn(const bf16* __restrict__ Qf,
                                                  const bf16* __restrict__ Kf,
                                                  const bf16* __restrict__ Vf,
                                                  const float* __restrict__ mbias,
                                                  const int* __restrict__ mask,
                                                  bf16* __restrict__ ctxP,
                                                  float* __restrict__ ls) {
    // [0,8192): buf0 K|V   [8192,16384): buf1 K|V   (elems; 4096 K + 4096 V)
    __shared__ bf16 sm[16384];
    __shared__ float mbL[1024];    // this half's mbias keys (4KB)

    int tid = threadIdx.x;
    int wave = tid >> 6, lane = tid & 63;
    int lrow = lane & 15, quad = lane >> 4;
    // XCD swizzle: 1024 blocks = 8 xcd * (4 bh * 16 qblk * 2 kh)
    int bid = blockIdx.x;
    int xcd = bid & 7, seq = bid >> 3;          // seq 0..127
    int bh  = xcd * 4 + (seq >> 5);             // 0..31
    int rest = seq & 31;
    int qblk = rest >> 1;                       // 0..15
    int kh   = rest & 1;                        // key half
    int b  = bh >> 4;
    int q0 = qblk * 128 + wave * 32;

    const float* mbp = mbias + b * N_ + kh * 1024;
    const bf16* kbase = Kf + (size_t)bh * 262144 + (size_t)kh * 131072;
    const bf16* vbase = Vf + (size_t)bh * 262144 + (size_t)kh * 131072;

    // Q B-frags from Qf (coalesced 16B loads), held all loop
    bf16x8 qf[2][4];
#pragma unroll
    for (int u = 0; u < 2; u++)
#pragma unroll
        for (int kf = 0; kf < 4; kf++)
            qf[u][kf] = *(const bf16x8*)(Qf + (size_t)(((size_t)bh * 128 + (q0 >> 4) + u) * 4 + kf) * 512 + lane * 8);

    bf16x8 ones;
#pragma unroll
    for (int j = 0; j < 8; j++) ones[j] = (bf16)1.0f;

    floatx4 zero4 = {0.f, 0.f, 0.f, 0.f};
    floatx4 O[2][8];
#pragma unroll
    for (int u = 0; u < 2; u++)
#pragma unroll
        for (int nf = 0; nf < 8; nf++) O[u][nf] = zero4;
    floatx4 Oext[2] = {zero4, zero4};   // row sums l[q] via ones-MFMA

    const float scale = 0.12751742f;    // (1/sqrt(128)) * log2(e)

    // ---- prologue: DMA tile 0 into buffer 0 + this half's mbias to LDS ----
    // K tile t: 8 contiguous frags at kbase + t*4096.
    // V tile t: kb64=t>>1, g=t&1: frag nf at vbase + kb64*8192 + nf*1024 + g*512.
#pragma unroll
    for (int i = 0; i < 2; i++) {
        int s = wave * 2 + i;                  // 0..7
        load_lds16(kbase + s * 512 + lane * 8, &sm[s * 512]);
        load_lds16(vbase + s * 1024 + lane * 8, &sm[4096 + s * 512]);
    }
    // mbias: 1024 floats = 4 segs of 256; one DMA per wave
    load_lds16((const bf16*)(mbp + wave * 256) + lane * 8, (bf16*)(mbL + wave * 256));

    for (int t = 0; t < 32; t++) {
        int cur = (t & 1) << 13;               // elems: 0 or 8192

        // ---- 1./2. wait my DMA(t) (+prologue mbias on t==0), barrier ----
        __builtin_amdgcn_s_waitcnt(WAITCNT_VM(0));
        __builtin_amdgcn_s_barrier();

        // ---- 3. prefetch DMA(t+1) into the other buffer ----
        if (t < 31) {
            int nxt = cur ^ 8192;
            int tn = t + 1;
            const bf16* ksrc = kbase + (size_t)tn * 4096;
            const bf16* vsrc = vbase + (size_t)(tn >> 1) * 8192 + (size_t)(tn & 1) * 512;
#pragma unroll
            for (int i = 0; i < 2; i++) {
                int s = wave * 2 + i;
                load_lds16(ksrc + s * 512 + lane * 8, &sm[nxt + s * 512]);
                load_lds16(vsrc + s * 1024 + lane * 8, &sm[nxt + 4096 + s * 512]);
            }
        }

        // ---- 4. S^T per 16-key tile; exp2; pack into K=32 B-frags ----
        bf16x8 pf[2];
#pragma unroll
        for (int s = 0; s < 2; s++) {
            floatx4 S0 = zero4, S1 = zero4;
            __builtin_amdgcn_s_setprio(1);
#pragma unroll
            for (int kf = 0; kf < 4; kf++) {
                bf16x8 kfr = *(const bf16x8*)(&sm[cur + ((s * 4 + kf) * 64 + lane) * 8]);
                S0 = MFMA32K(kfr, qf[0][kf], S0);
                S1 = MFMA32K(kfr, qf[1][kf], S1);
            }
            __builtin_amdgcn_s_setprio(0);
            float4 mb4 = *(const float4*)(mbL + t * 32 + s * 16 + quad * 4);
            const float* mbr = (const float*)&mb4;
            int o = s * 4;
#pragma unroll
            for (int r = 0; r < 4; r++) {
                float p0 = __builtin_amdgcn_exp2f(fmaf(S0[r], scale, mbr[r]));
                float p1 = __builtin_amdgcn_exp2f(fmaf(S1[r], scale, mbr[r]));
                pf[0][o + r] = (bf16)p0;
                pf[1][o + r] = (bf16)p1;
            }
        }

        // ---- l row-sums via ones-MFMA ----
        Oext[0] = MFMA32K(ones, pf[0], Oext[0]);
        Oext[1] = MFMA32K(ones, pf[1], Oext[1]);

        // ---- PV: O^T[d][q] += V^T P, full-rate K=32 ----
        __builtin_amdgcn_s_setprio(1);
#pragma unroll
        for (int nf = 0; nf < 8; nf++) {
            bf16x8 vfr = *(const bf16x8*)(&sm[cur + 4096 + (nf * 64 + lane) * 8]);
            O[0][nf] = MFMA32K(vfr, pf[0], O[0][nf]);
            O[1][nf] = MFMA32K(vfr, pf[1], O[1][nf]);
        }
        __builtin_amdgcn_s_setprio(0);
        // no end-of-iter barrier: next iter's barrier (after vmcnt) protects
        // buf[nxt] — every wave reaching it has finished this iter's reads
    }

    // ---- epilogue: normalize by OWN l + permuted-concat A-frag stores ----
    const int* mp = mask + b * N_;
    int h4 = (bh & 15) * 4;
    size_t qtb = (size_t)b * 128 + (q0 >> 4);
    bf16* ctx = ctxP + (size_t)kh * ((size_t)M_ * ALL_);
#pragma unroll
    for (int u = 0; u < 2; u++) {
        float lsum = Oext[u][0];
        int q = q0 + u * 16 + lrow;
        float rl = (mp[q] && lsum > 0.f) ? (1.0f / lsum) : 0.f;
#pragma unroll
        for (int g = 0; g < 4; g++) {
            bf16x8 w;
#pragma unroll
            for (int j = 0; j < 4; j++) {
                w[j]     = (bf16)(O[u][2 * g][j]     * rl);
                w[j + 4] = (bf16)(O[u][2 * g + 1][j] * rl);
            }
            *(bf16x8*)(ctx + ((qtb + u) * 64 + h4 + g) * 512 + lane * 8) = w;
        }
        // ls[kh][b][n][h], one writer per q-row
        if (quad == 0)
            ls[(((size_t)kh * 2 + b) * 2048 + q) * 16 + (bh & 15)] = lsum;
    }
}

// ---------------------------------------------------------------------------
// Kernel C: out = blend(ctxP0,ctxP1) @ Wo + bo, fp32 out. SPLIT-K x2
// (R17-proven structure, grid (256,4), 128 thr). Blend weights are constant
// per A-frag ROW (m=lrow) and per head (=k-group), so the combine folds into
// the A-frag load: a = wA*a1 + wB*a2, wA=l1/(l1+l2).
// ---------------------------------------------------------------------------
__global__ __launch_bounds__(128) void out_proj(const bf16* __restrict__ ctxP,
                                                const float* __restrict__ ls,
                                                const bf16* __restrict__ Wof,
                                                const float* __restrict__ bo,
                                                float* __restrict__ out) {
    __shared__ float red[512];         // wave1 partials: [nf2][r4][lane64]
    int tid = threadIdx.x;
    int wave = tid >> 6, lane = tid & 63;
    int lrow = lane & 15, quad = lane >> 4;
    int qt = blockIdx.x;               // 16-row tile
    int ct = blockIdx.y * 2;           // two 16-col tiles
    int r0 = qt * 16, c0 = ct * 16;
    int b = qt >> 7;
    int n = ((qt & 127) << 4) + lrow;  // within-batch row of this lane's A-frag

    // blend weights for the 8 heads this wave contracts (k = wave*32..+32)
    const float* ls0 = ls + (((size_t)b) * 2048 + n) * 16;
    const float* ls1 = ls + (((size_t)(2 + b)) * 2048 + n) * 16;
    float wA[8], wB[8];
#pragma unroll
    for (int hh = 0; hh < 8; hh++) {
        int h = wave * 8 + hh;
        float l1 = ls0[h], l2 = ls1[h];
        float sum = l1 + l2;
        float inv = (sum > 0.f) ? (1.f / sum) : 0.f;
        wA[hh] = l1 * inv;
        wB[hh] = l2 * inv;
    }

    floatx4 zero4 = {0.f, 0.f, 0.f, 0.f};
    floatx4 acc[2] = {zero4, zero4};
    const bf16* ap0 = ctxP + ((size_t)qt * 64 + wave * 32) * 512 + lane * 8;
    const bf16* ap1 = ap0 + (size_t)M_ * ALL_;
    const bf16* b0 = Wof + ((size_t)ct * 64 + wave * 32) * 512 + lane * 8;
    const bf16* b1 = b0 + (size_t)64 * 512;
#pragma unroll
    for (int kf = 0; kf < 32; kf++) {
        bf16x8 a1 = *(const bf16x8*)(ap0 + (size_t)kf * 512);
        bf16x8 a2 = *(const bf16x8*)(ap1 + (size_t)kf * 512);
        float wa = wA[kf >> 2], wb = wB[kf >> 2];   // kf fully unrolled: static idx
        bf16x8 a;
#pragma unroll
        for (int j = 0; j < 8; j++)
            a[j] = (bf16)(wa * (float)a1[j] + wb * (float)a2[j]);
        bf16x8 w0 = *(const bf16x8*)(b0 + (size_t)kf * 512);
        bf16x8 w1 = *(const bf16x8*)(b1 + (size_t)kf * 512);
        acc[0] = MFMA32K(a, w0, acc[0]);
        acc[1] = MFMA32K(a, w1, acc[1]);
    }
    if (wave == 1) {
#pragma unroll
        for (int nf = 0; nf < 2; nf++)
#pragma unroll
            for (int r = 0; r < 4; r++)
                red[nf * 256 + r * 64 + lane] = acc[nf][r];
    }
    __syncthreads();
    if (wave == 0) {
#pragma unroll
        for (int nf = 0; nf < 2; nf++) {
            int col = c0 + nf * 16 + lrow;
            float bv = bo[col];
#pragma unroll
            for (int r = 0; r < 4; r++) {
                int m = r0 + quad * 4 + r;
                out[(size_t)m * 128 + col] = acc[nf][r] + red[nf * 256 + r * 64 + lane] + bv;
            }
        }
    }
}

// ---------------------------------------------------------------------------
extern "C" void kernel_launch(void* const* d_in, const int* in_sizes, int n_in,
                              void* d_out, int out_size, void* d_ws, size_t ws_size,
                              hipStream_t stream) {
    const float* x    = (const float*)d_in[0];
    const int*   mask = (const int*)d_in[1];
    const float* Wq   = (const float*)d_in[2];
    const float* bq   = (const float*)d_in[3];
    const float* Wk   = (const float*)d_in[4];
    const float* bk   = (const float*)d_in[5];
    const float* Wv   = (const float*)d_in[6];
    const float* bv   = (const float*)d_in[7];
    const float* Wo   = (const float*)d_in[8];
    const float* bo   = (const float*)d_in[9];
    float* out = (float*)d_out;

    char* ws = (char*)d_ws;
    size_t off = 0;
    bf16* Wqf = (bf16*)(ws + off); off += (size_t)262144 * 2;
    bf16* Wkf = (bf16*)(ws + off); off += (size_t)262144 * 2;
    bf16* Wvf = (bf16*)(ws + off); off += (size_t)262144 * 2;
    bf16* Wof = (bf16*)(ws + off); off += (size_t)262144 * 2;
    bf16* xf  = (bf16*)(ws + off); off += (size_t)524288 * 2;
    size_t qkv_elems = (size_t)BH_ * N_ * 128;           // 8.4M
    bf16* Qf  = (bf16*)(ws + off); off += qkv_elems * 2; // fragment-major
    bf16* Kf  = (bf16*)(ws + off); off += qkv_elems * 2;
    bf16* Vf  = (bf16*)(ws + off); off += qkv_elems * 2;
    bf16* ctxP = (bf16*)(ws + off); off += (size_t)M_ * ALL_ * 2 * 2;  // 2 partials
    float* mbias = (float*)(ws + off); off += (size_t)B_ * N_ * 4;
    float* ls = (float*)(ws + off); off += (size_t)2 * 2 * 2048 * 16 * 4;
    (void)ws_size; (void)in_sizes; (void)n_in; (void)out_size;

    prep_weights<<<368, 256, 0, stream>>>(x, Wq, Wk, Wv, Wo, mask,
                                          Wqf, Wkf, Wvf, Wof, xf, mbias);

    qkv_proj<<<dim3(64, 32, 3), 256, 0, stream>>>(xf, bq, bk, bv, Wqf, Wkf, Wvf,
                                                  Qf, Kf, Vf);

    flash_attn<<<1024, 256, 0, stream>>>(Qf, Kf, Vf, mbias, mask, ctxP, ls);

    out_proj<<<dim3(256, 4), 128, 0, stream>>>(ctxP, ls, Wof, bo, out);
}

// Round 3
// 172.971 us; speedup vs baseline: 1.2563x; 1.1399x over previous
//
#include <hip/hip_runtime.h>
#include <hip/hip_bf16.h>

// Problem constants
#define B_   2
#define N_   2048
#define D_   128
#define H_   16
#define ALL_ 2048
#define M_   (B_*N_)    // 4096 total rows
#define BH_  (B_*H_)    // 32 (batch*heads)

typedef __bf16 bf16;
typedef __bf16 bf16x8 __attribute__((ext_vector_type(8)));
typedef __bf16 bf16x4 __attribute__((ext_vector_type(4)));
typedef float  floatx4 __attribute__((ext_vector_type(4)));

#define MFMA32K(a,b,c) __builtin_amdgcn_mfma_f32_16x16x32_bf16((a),(b),(c),0,0,0)

// async global->LDS DMA, 16B per lane (m97 pattern).
// Global address is PER-LANE (base + lane*8 bf16); LDS addr wave-uniform.
__device__ inline void load_lds16(const bf16* g, bf16* l) {
    __builtin_amdgcn_global_load_lds((const __attribute__((address_space(1))) void*)g,
                                     (__attribute__((address_space(3))) void*)l, 16, 0, 0);
}

#define WAITCNT_VM(n) ((0xF << 8) | (0x7 << 4) | (n))

// ---------------------------------------------------------------------------
// FRAGMENT-MAJOR LAYOUTS:
//  A/B-frag canonical (16x16x32): elem j of lane (lrow=lane&15,quad=lane>>4)
//    A[m=lrow][k=kf*32+quad*8+j]  /  B[k=kf*32+quad*8+j][n=lrow]
//  Wf  (Wq/Wk/Wv): [ct 128][kf 4][lane][8]  canonical
//  xf:  [rt 256][kf 4][lane][8]             canonical
//  Qf/Kf: [bh][t 128][kf 4][lane][8]        canonical
//  Vf:  [bh][kb 32][nf 8][g 2][lane][8]  PERMUTED k:
//        elem j = V[key=kb*64+(2g+(j>>2))*16+quad*4+(j&3)][d=nf*16+lrow]
//  ctxf: [qt 256][kf 64][lane][8]        PERMUTED k (same map over d):
//        elem j = ctx[q=qt*16+lrow][d' = (kf&3)*32+(j>>2)*16+quad*4+(j&3)]
//        (head = kf>>2) — written DIRECTLY from flash O accumulators.
//  Wof: [ct 8][kf 64][lane][8]           PERMUTED k to MATCH ctxf:
//        elem j = Wo[k = kf*32+(j>>2)*16+quad*4+(j&3)][col=ct*16+lrow]
//  MFMA contraction is invariant when A and B agree on the k-permutation.
//  mbias pre-scaled by log2(e) (exp2 path).
// ---------------------------------------------------------------------------

// ---------------------------------------------------------------------------
// Kernel T: prep — unchanged.
// ---------------------------------------------------------------------------
__global__ __launch_bounds__(256) void prep_weights(const float* __restrict__ x,
                                                    const float* __restrict__ Wq,
                                                    const float* __restrict__ Wk,
                                                    const float* __restrict__ Wv,
                                                    const float* __restrict__ Wo,
                                                    const int* __restrict__ mask,
                                                    bf16* __restrict__ Wqf,
                                                    bf16* __restrict__ Wkf,
                                                    bf16* __restrict__ Wvf,
                                                    bf16* __restrict__ Wof,
                                                    bf16* __restrict__ xf,
                                                    float* __restrict__ mbias) {
    __shared__ bf16 pw[16896];
    int bid = blockIdx.x, t = threadIdx.x;
    int lane = t & 63, wave = t >> 6;
    int lrow = lane & 15, quad = lane >> 4;

    if (bid < 192) {
        // ---- Wq/Wk/Wv [128][2048]: block = 64 k-rows (half) x 64 cols ----
        int m = bid / 64, rest = bid % 64;
        int cg = rest >> 1, kh = rest & 1;
        const float* W = (m == 0) ? Wq : (m == 1) ? Wk : Wv;
        bf16* Wf       = (m == 0) ? Wqf : (m == 1) ? Wkf : Wvf;
        int slot = t & 15, rowb = t >> 4;
#pragma unroll
        for (int i = 0; i < 4; i++) {
            int rl_ = rowb + i * 16;           // local k-row 0..63
            float4 v = *(const float4*)(W + (size_t)(kh * 64 + rl_) * 2048 + cg * 64 + slot * 4);
            bf16x4 o; o[0]=(bf16)v.x; o[1]=(bf16)v.y; o[2]=(bf16)v.z; o[3]=(bf16)v.w;
            *(bf16x4*)(&pw[rl_ * 68 + slot * 4]) = o;   // tile [k 64][col 64] stride 68
        }
        __syncthreads();
        int ctl = wave;                        // local col-tile 0..3
#pragma unroll
        for (int kfl = 0; kfl < 2; kfl++) {
            bf16x8 w;
#pragma unroll
            for (int j = 0; j < 8; j++) w[j] = pw[(kfl * 32 + quad * 8 + j) * 68 + ctl * 16 + lrow];
            *(bf16x8*)(Wf + (size_t)((cg * 4 + ctl) * 4 + kh * 2 + kfl) * 512 + lane * 8) = w;
        }
    } else if (bid < 224) {
        // ---- Wo [2048][128]: block = 128 k-rows x 64-col half, PERMUTED ----
        int idx = bid - 192;
        int kb16 = idx >> 1, ch = idx & 1;
        int k0 = kb16 * 128;
        int slot = t & 15, rowb = t >> 4;
#pragma unroll
        for (int i = 0; i < 8; i++) {
            int r = rowb + i * 16;             // 0..127
            float4 v = *(const float4*)(Wo + (size_t)(k0 + r) * 128 + ch * 64 + slot * 4);
            bf16x4 o; o[0]=(bf16)v.x; o[1]=(bf16)v.y; o[2]=(bf16)v.z; o[3]=(bf16)v.w;
            *(bf16x4*)(&pw[r * 68 + slot * 4]) = o;     // tile [k 128][col 64] stride 68
        }
        __syncthreads();
        int ctl = wave;
        int ct = ch * 4 + ctl;
#pragma unroll
        for (int kfl = 0; kfl < 4; kfl++) {
            bf16x8 w;
            // PERMUTED k to match flash's O-concat A-frags:
            // elem j <- k = kfl*32 + (j>>2)*16 + quad*4 + (j&3)
#pragma unroll
            for (int j = 0; j < 8; j++)
                w[j] = pw[(kfl * 32 + ((j >> 2) << 4) + quad * 4 + (j & 3)) * 68 + ctl * 16 + lrow];
            *(bf16x8*)(Wof + (size_t)(ct * 64 + kb16 * 4 + kfl) * 512 + lane * 8) = w;
        }
    } else if (bid < 352) {
        // ---- x [4096][128] fp32 -> xf frags, 32 rows per block ----
        int idx = bid - 224, r0 = idx * 32;
        int slot = t & 31, rowb = t >> 5;
#pragma unroll
        for (int i = 0; i < 4; i++) {
            int r = rowb + i * 8;              // 0..31
            float4 v = *(const float4*)(x + (size_t)(r0 + r) * 128 + slot * 4);
            bf16x4 o; o[0]=(bf16)v.x; o[1]=(bf16)v.y; o[2]=(bf16)v.z; o[3]=(bf16)v.w;
            *(bf16x4*)(&pw[r * 136 + slot * 4]) = o;    // tile [row 32][col 128] stride 136
        }
        __syncthreads();
        int rtl = wave >> 1;                   // 2 row-tiles of 16
        int kf2 = (wave & 1) * 2;
#pragma unroll
        for (int kfl = 0; kfl < 2; kfl++) {
            int kf = kf2 + kfl;
            bf16x8 w = *(const bf16x8*)(&pw[(rtl * 16 + lrow) * 136 + kf * 32 + quad * 8]);
            *(bf16x8*)(xf + (size_t)((idx * 2 + rtl) * 4 + kf) * 512 + lane * 8) = w;
        }
    } else {
        int e = (bid - 352) * 256 + t;
        // log2-domain: exp2(-43.28) ~ 9e-14 ~ 0
        mbias[e] = mask[e] ? 0.0f : -43.2808512f;
    }
}

// ---------------------------------------------------------------------------
// Kernel A: Q/K/V projection — Z-FUSED: one block computes Q,K,V tiles for
// its (r0b,c0), reading the xf A-frags ONCE (was 3x across the z-grid).
// Grid (64,32) = 2048 blocks (was 6144). MFMA count / epilogue layouts
// unchanged; per-z epilogues separated by barriers (tile reuse).
// ---------------------------------------------------------------------------
__global__ __launch_bounds__(256) void qkv_proj(const bf16* __restrict__ xf,
                                                const float* __restrict__ bq,
                                                const float* __restrict__ bk,
                                                const float* __restrict__ bv,
                                                const bf16* __restrict__ Wqf,
                                                const bf16* __restrict__ Wkf,
                                                const bf16* __restrict__ Wvf,
                                                bf16* __restrict__ Qf,
                                                bf16* __restrict__ Kf,
                                                bf16* __restrict__ Vf) {
    __shared__ bf16 tile[64][72];

    int tid = threadIdx.x;
    int wave = tid >> 6, lane = tid & 63;
    int lrow = lane & 15, quad = lane >> 4;
    int r0b = blockIdx.x * 64;
    int c0 = blockIdx.y * 64;
    int cg4 = c0 >> 4;

    int rt = (r0b >> 4) + wave;
    bf16x8 a[4];
#pragma unroll
    for (int kf = 0; kf < 4; kf++)
        a[kf] = *(const bf16x8*)(xf + (size_t)(rt * 4 + kf) * 512 + lane * 8);

    int bb = r0b >> 11;
    int h  = c0 >> 7;
    int bhw = bb * 16 + h;
    int tile16 = (r0b & 2047) >> 4;
    int kbt = (r0b & 2047) >> 6;
    floatx4 zero4 = {0.f, 0.f, 0.f, 0.f};

#pragma unroll
    for (int z = 0; z < 3; z++) {
        const float* bias = (z == 0) ? bq : (z == 1) ? bk : bv;
        const bf16*  Wf   = (z == 0) ? Wqf : (z == 1) ? Wkf : Wvf;

        floatx4 acc[4] = {zero4, zero4, zero4, zero4};
#pragma unroll
        for (int kf = 0; kf < 4; kf++) {
#pragma unroll
            for (int nf = 0; nf < 4; nf++) {
                bf16x8 b = *(const bf16x8*)(Wf + (size_t)((cg4 + nf) * 4 + kf) * 512 + lane * 8);
                acc[nf] = MFMA32K(a[kf], b, acc[nf]);
            }
        }

#pragma unroll
        for (int nf = 0; nf < 4; nf++) {
            int col = nf * 16 + lrow;
            float bvv = bias[c0 + col];
#pragma unroll
            for (int r = 0; r < 4; r++) {
                int row = wave * 16 + quad * 4 + r;
                bf16 val = (bf16)(acc[nf][r] + bvv);
                if (z < 2) tile[row][col] = val;
                else       tile[col][row] = val;
            }
        }
        __syncthreads();

        if (z < 2) {
            bf16* dst = (z == 0) ? Qf : Kf;
            int s = wave;
            int kfbase = (c0 & 127) >> 5;
            size_t fbase = ((size_t)bhw * 128 + tile16 + s) * 4 + kfbase;
#pragma unroll
            for (int kfl = 0; kfl < 2; kfl++) {
                bf16x8 w = *(const bf16x8*)(&tile[s * 16 + lrow][kfl * 32 + quad * 8]);
                *(bf16x8*)(dst + (fbase + kfl) * 512 + lane * 8) = w;
            }
        } else {
            int nfl = wave;
            int nfbase = (c0 & 127) >> 4;
            size_t fbase = (((size_t)bhw * 32 + kbt) * 8 + (nfbase + nfl)) * 2;
#pragma unroll
            for (int g = 0; g < 2; g++) {
                bf16x4 a0 = *(const bf16x4*)(&tile[nfl * 16 + lrow][g * 32 + quad * 4]);
                bf16x4 a1 = *(const bf16x4*)(&tile[nfl * 16 + lrow][g * 32 + 16 + quad * 4]);
                bf16x8 w;
                w[0]=a0[0]; w[1]=a0[1]; w[2]=a0[2]; w[3]=a0[3];
                w[4]=a1[0]; w[5]=a1[1]; w[6]=a1[2]; w[7]=a1[3];
                *(bf16x8*)(Vf + (fbase + g) * 512 + lane * 8) = w;
            }
        }
        if (z < 2) __syncthreads();   // protect tile before next z overwrites
    }
}

// ---------------------------------------------------------------------------
// Kernel B: flash attention — R0 KVBLK=64 structure (proven 85.4 µs), with
// V MOVED OUT OF LDS. R1/R2 lesson: occupancy is reg-granule-locked at
// 2 waves/SIMD regardless of LDS/grid, so the lever is pipe-time, and the
// most-loaded pipe was LDS (34 ds_read_b128/wave/iter, ~51% of CU cycles).
// All 4 waves read the IDENTICAL 16KB V-tile -> per-wave global loads hit
// L1/L2 (demand ~20 B/cyc/CU << L2's 56). V-loads issue at iter top, used
// ~1500cy later in PV: L2 latency fully hidden, no new sync. LDS traffic
// -47%; VMEM pipe (idle before) absorbs V. Same frag values, same summation
// order -> bit-identical output. LDS 73728 -> 40960 B.
// __launch_bounds__(256,2): pin the 256-reg budget (vreg adds 64 VGPR;
// without the pin the compiler may chase 3 waves/EU and spill).
// ---------------------------------------------------------------------------
__global__ __launch_bounds__(256, 2) void flash_attn(const bf16* __restrict__ Qf,
                                                     const bf16* __restrict__ Kf,
                                                     const bf16* __restrict__ Vf,
                                                     const float* __restrict__ mbias,
                                                     const int* __restrict__ mask,
                                                     bf16* __restrict__ ctxf) {
    // [0,8192): K buf0  [8192,16384): K buf1  [16384,20480): mbias (2048 f32)
    __shared__ bf16 sm[20480];
    float* mbL = (float*)&sm[16384];

    int tid = threadIdx.x;
    int wave = tid >> 6, lane = tid & 63;
    int lrow = lane & 15, quad = lane >> 4;
    // XCD swizzle: 512 blocks = 8 xcd * (4 bh * 16 qblk)
    int bid = blockIdx.x;
    int xcd = bid & 7, seq = bid >> 3;          // seq 0..63
    int bh  = xcd * 4 + (seq >> 4);             // 0..31
    int qblk = seq & 15;                        // 0..15
    int b  = bh >> 4;
    int q0 = qblk * 128 + wave * 32;

    const float* mbp = mbias + b * N_;
    const bf16* kbase = Kf + (size_t)bh * 262144;
    const bf16* vbase = Vf + (size_t)bh * 262144;

    // Q B-frags from Qf (coalesced 16B loads), held all loop
    bf16x8 qf[2][4];
#pragma unroll
    for (int u = 0; u < 2; u++)
#pragma unroll
        for (int kf = 0; kf < 4; kf++)
            qf[u][kf] = *(const bf16x8*)(Qf + (size_t)(((size_t)bh * 128 + (q0 >> 4) + u) * 4 + kf) * 512 + lane * 8);

    bf16x8 ones;
#pragma unroll
    for (int j = 0; j < 8; j++) ones[j] = (bf16)1.0f;

    floatx4 zero4 = {0.f, 0.f, 0.f, 0.f};
    floatx4 O[2][8];
#pragma unroll
    for (int u = 0; u < 2; u++)
#pragma unroll
        for (int nf = 0; nf < 8; nf++) O[u][nf] = zero4;
    floatx4 Oext[2] = {zero4, zero4};   // row sums l[q] via ones-MFMA

    const float scale = 0.12751742f;    // (1/sqrt(128)) * log2(e)

    // ---- prologue: DMA K(0) into buffer 0 + mbias row into LDS ----
#pragma unroll
    for (int i = 0; i < 4; i++) {
        int seg = wave * 4 + i;                // 0..15, 1KB each
        load_lds16(kbase + seg * 512 + lane * 8, &sm[seg * 512]);
    }
#pragma unroll
    for (int i = 0; i < 2; i++) {
        int seg = wave * 2 + i;                // 0..7, 256 floats (1KB) each
        load_lds16((const bf16*)(mbp + seg * 256) + lane * 8, (bf16*)(mbL + seg * 256));
    }

    for (int kb = 0; kb < 32; kb++) {
        int cur = (kb & 1) << 13;              // elems: 0 or 8192

        // ---- 1./2. wait my K-DMA(kb) (+prologue mbias on kb==0), barrier --
        // V(kb-1) reg-loads already retired (consumed by PV of kb-1).
        __builtin_amdgcn_s_waitcnt(WAITCNT_VM(0));
        __builtin_amdgcn_s_barrier();

        // ---- 3. prefetch K-DMA(kb+1) into the other buffer ----
        if (kb < 31) {
            int nxt = cur ^ 8192;
            const bf16* ksrc = kbase + (size_t)(kb + 1) * 8192;
#pragma unroll
            for (int i = 0; i < 4; i++) {
                int seg = wave * 4 + i;
                load_lds16(ksrc + seg * 512 + lane * 8, &sm[nxt + seg * 512]);
            }
        }

        // ---- 3b. V(kb) global->reg (L1-shared across the 4 waves); used in
        // PV ~1500cy below -> L2 latency hidden; compiler inserts the wait.
        const bf16* vsrc = vbase + (size_t)kb * 8192 + lane * 8;
        bf16x8 vreg[16];
#pragma unroll
        for (int f = 0; f < 16; f++)
            vreg[f] = *(const bf16x8*)(vsrc + f * 512);

        // ---- 4. S^T per 16-key tile; exp2; pack into K=32 B-frags ----
        bf16x8 pf[2][2];
#pragma unroll
        for (int s = 0; s < 4; s++) {
            floatx4 S0 = zero4, S1 = zero4;
            __builtin_amdgcn_s_setprio(1);
#pragma unroll
            for (int kf = 0; kf < 4; kf++) {
                bf16x8 kfr = *(const bf16x8*)(&sm[cur + ((s * 4 + kf) * 64 + lane) * 8]);
                S0 = MFMA32K(kfr, qf[0][kf], S0);
                S1 = MFMA32K(kfr, qf[1][kf], S1);
            }
            __builtin_amdgcn_s_setprio(0);
            float4 mb4 = *(const float4*)(mbL + kb * 64 + s * 16 + quad * 4);  // LDS (lgkmcnt)
            const float* mbr = (const float*)&mb4;
            int g = s >> 1, o = (s & 1) * 4;
#pragma unroll
            for (int r = 0; r < 4; r++) {
                float p0 = __builtin_amdgcn_exp2f(fmaf(S0[r], scale, mbr[r]));
                float p1 = __builtin_amdgcn_exp2f(fmaf(S1[r], scale, mbr[r]));
                pf[0][g][o + r] = (bf16)p0;
                pf[1][g][o + r] = (bf16)p1;
            }
        }

        // ---- l row-sums via ones-MFMA ----
#pragma unroll
        for (int g = 0; g < 2; g++) {
            Oext[0] = MFMA32K(ones, pf[0][g], Oext[0]);
            Oext[1] = MFMA32K(ones, pf[1][g], Oext[1]);
        }

        // ---- PV: O^T[d][q] += V^T P, full-rate K=32, V from registers ----
        __builtin_amdgcn_s_setprio(1);
#pragma unroll
        for (int nf = 0; nf < 8; nf++) {
#pragma unroll
            for (int g = 0; g < 2; g++) {
                O[0][nf] = MFMA32K(vreg[nf * 2 + g], pf[0][g], O[0][nf]);
                O[1][nf] = MFMA32K(vreg[nf * 2 + g], pf[1][g], O[1][nf]);
            }
        }
        __builtin_amdgcn_s_setprio(0);
        // no end-of-iter barrier: next iter's barrier (after vmcnt) protects
        // K buf[nxt] — every wave reaching it has finished this iter's reads
    }

    // ---- epilogue: normalize + DIRECT permuted-concat A-frag stores ----
    const int* mp = mask + b * N_;
    int h4 = (bh & 15) * 4;
    size_t qtb = (size_t)b * 128 + (q0 >> 4);
#pragma unroll
    for (int u = 0; u < 2; u++) {
        float lsum = Oext[u][0];
        int q = q0 + u * 16 + lrow;
        float rl = (mp[q] && lsum > 0.f) ? (1.0f / lsum) : 0.f;
#pragma unroll
        for (int g = 0; g < 4; g++) {
            bf16x8 w;
#pragma unroll
            for (int j = 0; j < 4; j++) {
                w[j]     = (bf16)(O[u][2 * g][j]     * rl);
                w[j + 4] = (bf16)(O[u][2 * g + 1][j] * rl);
            }
            *(bf16x8*)(ctxf + ((qtb + u) * 64 + h4 + g) * 512 + lane * 8) = w;
        }
    }
}

// ---------------------------------------------------------------------------
// Kernel C: out = ctx @ Wo + bo, fp32 out. SPLIT-K x2 — exact R0 revert
// (the 256-block restructure in R1 cost ~20 µs; this (256,4)x128thr form
// is the best measured). ctxf/Wof carry a matching k-permutation, opaque.
// ---------------------------------------------------------------------------
__global__ __launch_bounds__(128) void out_proj(const bf16* __restrict__ ctxf,
                                                const bf16* __restrict__ Wof,
                                                const float* __restrict__ bo,
                                                float* __restrict__ out) {
    __shared__ float red[512];         // wave1 partials: [nf2][r4][lane64]
    int tid = threadIdx.x;
    int wave = tid >> 6, lane = tid & 63;
    int lrow = lane & 15, quad = lane >> 4;
    int qt = blockIdx.x;               // 16-row tile
    int ct = blockIdx.y * 2;           // two 16-col tiles
    int r0 = qt * 16, c0 = ct * 16;

    floatx4 zero4 = {0.f, 0.f, 0.f, 0.f};
    floatx4 acc[2] = {zero4, zero4};
    const bf16* ap = ctxf + ((size_t)qt * 64 + wave * 32) * 512 + lane * 8;
    const bf16* b0 = Wof + ((size_t)ct * 64 + wave * 32) * 512 + lane * 8;
    const bf16* b1 = b0 + (size_t)64 * 512;
#pragma unroll 4
    for (int kf = 0; kf < 32; kf++) {
        bf16x8 a  = *(const bf16x8*)(ap + (size_t)kf * 512);
        bf16x8 w0 = *(const bf16x8*)(b0 + (size_t)kf * 512);
        bf16x8 w1 = *(const bf16x8*)(b1 + (size_t)kf * 512);
        acc[0] = MFMA32K(a, w0, acc[0]);
        acc[1] = MFMA32K(a, w1, acc[1]);
    }
    if (wave == 1) {
#pragma unroll
        for (int nf = 0; nf < 2; nf++)
#pragma unroll
            for (int r = 0; r < 4; r++)
                red[nf * 256 + r * 64 + lane] = acc[nf][r];
    }
    __syncthreads();
    if (wave == 0) {
#pragma unroll
        for (int nf = 0; nf < 2; nf++) {
            int col = c0 + nf * 16 + lrow;
            float bv = bo[col];
#pragma unroll
            for (int r = 0; r < 4; r++) {
                int m = r0 + quad * 4 + r;
                out[(size_t)m * 128 + col] = acc[nf][r] + red[nf * 256 + r * 64 + lane] + bv;
            }
        }
    }
}

// ---------------------------------------------------------------------------
extern "C" void kernel_launch(void* const* d_in, const int* in_sizes, int n_in,
                              void* d_out, int out_size, void* d_ws, size_t ws_size,
                              hipStream_t stream) {
    const float* x    = (const float*)d_in[0];
    const int*   mask = (const int*)d_in[1];
    const float* Wq   = (const float*)d_in[2];
    const float* bq   = (const float*)d_in[3];
    const float* Wk   = (const float*)d_in[4];
    const float* bk   = (const float*)d_in[5];
    const float* Wv   = (const float*)d_in[6];
    const float* bv   = (const float*)d_in[7];
    const float* Wo   = (const float*)d_in[8];
    const float* bo   = (const float*)d_in[9];
    float* out = (float*)d_out;

    char* ws = (char*)d_ws;
    size_t off = 0;
    bf16* Wqf = (bf16*)(ws + off); off += (size_t)262144 * 2;
    bf16* Wkf = (bf16*)(ws + off); off += (size_t)262144 * 2;
    bf16* Wvf = (bf16*)(ws + off); off += (size_t)262144 * 2;
    bf16* Wof = (bf16*)(ws + off); off += (size_t)262144 * 2;
    bf16* xf  = (bf16*)(ws + off); off += (size_t)524288 * 2;
    size_t qkv_elems = (size_t)BH_ * N_ * 128;           // 8.4M
    bf16* Qf  = (bf16*)(ws + off); off += qkv_elems * 2; // fragment-major
    bf16* Kf  = (bf16*)(ws + off); off += qkv_elems * 2;
    bf16* Vf  = (bf16*)(ws + off); off += qkv_elems * 2;
    bf16* ctxf = (bf16*)(ws + off); off += (size_t)M_ * ALL_ * 2;
    float* mbias = (float*)(ws + off); off += (size_t)B_ * N_ * 4;
    (void)ws_size; (void)in_sizes; (void)n_in; (void)out_size;

    prep_weights<<<368, 256, 0, stream>>>(x, Wq, Wk, Wv, Wo, mask,
                                          Wqf, Wkf, Wvf, Wof, xf, mbias);

    qkv_proj<<<dim3(64, 32), 256, 0, stream>>>(xf, bq, bk, bv, Wqf, Wkf, Wvf,
                                               Qf, Kf, Vf);

    flash_attn<<<512, 256, 0, stream>>>(Qf, Kf, Vf, mbias, mask, ctxf);

    out_proj<<<dim3(256, 4), 128, 0, stream>>>(ctxf, Wof, bo, out);
}